// Round 10
// baseline (315.815 us; speedup 1.0000x reference)
//
#include <hip/hip_runtime.h>
#include <stdint.h>

#define B 4
#define HW 128
#define C 256
#define NTOK 16384
#define MALL 65536
#define HEADS 8
#define DH 32

typedef float f32x4 __attribute__((ext_vector_type(4)));
typedef short s16x8 __attribute__((ext_vector_type(8)));
typedef short s16x4 __attribute__((ext_vector_type(4)));
typedef __bf16 bf16x8 __attribute__((ext_vector_type(8)));

__device__ __forceinline__ float bf2f(unsigned short u) {
  union { unsigned int i; float f; } x;
  x.i = ((unsigned int)u) << 16;
  return x.f;
}
__device__ __forceinline__ unsigned short f2bf(float f) {
  union { float f; unsigned int i; } x;
  x.f = f;
  unsigned int lsb = (x.i >> 16) & 1u;
  unsigned int r = x.i + 0x7fffu + lsb;
  return (unsigned short)(r >> 16);
}

__device__ __forceinline__ void gload_lds16(const void* g, void* l) {
  auto gp = reinterpret_cast<const __attribute__((address_space(1))) unsigned int*>(
      reinterpret_cast<uintptr_t>(g));
  auto lp = reinterpret_cast<__attribute__((address_space(3))) unsigned int*>(
      reinterpret_cast<uintptr_t>(l));
  __builtin_amdgcn_global_load_lds(gp, lp, 16, 0, 0);
}

#define CFENCE asm volatile("" ::: "memory")
#define LDSBAR()                                        \
  do {                                                  \
    asm volatile("s_waitcnt lgkmcnt(0)" ::: "memory");  \
    __builtin_amdgcn_s_barrier();                       \
    CFENCE;                                             \
  } while (0)

// ---------------- weight prep: transpose+cast ----------------
__global__ __launch_bounds__(256) void prep_w_kernel(
    const float* __restrict__ wq, const float* __restrict__ wk, const float* __restrict__ wv,
    const float* __restrict__ wproj, const float* __restrict__ w1, const float* __restrict__ w2,
    unsigned short* __restrict__ wqkvT, unsigned short* __restrict__ wprojT,
    unsigned short* __restrict__ w1b, unsigned short* __restrict__ w2b) {
  const int idx = blockIdx.x * 256 + threadIdx.x;  // 0..65535
  const int mat = blockIdx.y;
  const int n = idx >> 8, k = idx & 255;
  switch (mat) {
    case 0: wqkvT[idx] = f2bf(wq[k * 256 + n]); break;
    case 1: wqkvT[65536 + idx] = f2bf(wk[k * 256 + n]); break;
    case 2: wqkvT[131072 + idx] = f2bf(wv[k * 256 + n]); break;
    case 3: wprojT[idx] = f2bf(wproj[k * 256 + n]); break;
    case 4: w1b[idx] = f2bf(w1[idx]); break;
    case 5: w2b[idx] = f2bf(w2[idx]); break;
  }
}

// ---------------- transpose mask [C][N] -> [N][C] bf16 ----------------
__global__ __launch_bounds__(1024) void tmask_kernel(const float* __restrict__ mask,
                                                     unsigned short* __restrict__ mT) {
  __shared__ float tile[32][33];
  const int p0 = blockIdx.x * 32, c0 = blockIdx.y * 32;
  const int tx = threadIdx.x & 31, ty = threadIdx.x >> 5;
  tile[ty][tx] = mask[(size_t)(c0 + ty) * NTOK + p0 + tx];
  __syncthreads();
  mT[(size_t)(p0 + ty) * C + c0 + tx] = f2bf(tile[tx][ty]);
}

// ================ 128x128 BK32 4-wave GEMM: qkv (A = f32 x, cast in staging) ============
__global__ __launch_bounds__(256) void gemm128_qkv_kernel(
    const float* __restrict__ X, const unsigned short* __restrict__ Bt,
    unsigned short* __restrict__ q, unsigned short* __restrict__ k,
    unsigned short* __restrict__ v) {
  __shared__ alignas(16) unsigned short smem[16384];  // 32KB: A 2x4096, B 2x4096 (ushort)
  const int nwg = gridDim.x;
  const int bid = blockIdx.x;
  const int qd = nwg >> 3, rr = nwg & 7;
  const int xcd = bid & 7, sidx = bid >> 3;
  const int swz = (xcd < rr ? xcd * (qd + 1) : rr * (qd + 1) + (xcd - rr) * qd) + sidx;
  const int m0 = (swz / 6) * 128;
  const int n0 = (swz % 6) * 128;
  const int t = threadIdx.x;
  const int w = t >> 6, l = t & 63;
  const int wr = w >> 1, wc = w & 1;
  const int lr = l & 15, lg = l >> 4;

  // A-path (regs + per-lane ds_write): thread t covers row r=t>>1, phys slots (t&1)*2, +1
  const int r = t >> 1;
  const int rm3 = r & 3;
  const int p0s = (((t & 1) * 2 + 0) ^ rm3);
  const int p1s = (((t & 1) * 2 + 1) ^ rm3);
  // B-path (global_load_lds, lane-stride-16 dest): instr v covers row v*64 + (t>>2),
  // phys slot t&3, logical slot (t&3) ^ (row&3). 64%4==0 so same swizzle both instrs.
  const int br = t >> 2;
  const int bsl = (t & 3) ^ (br & 3);

  f32x4 va0, va1, va2, va3;
  auto ALOAD = [&](int kt) {
    const float* src = X + (size_t)(m0 + r) * 256 + kt * 32;
    va0 = *(const f32x4*)(src + p0s * 8);
    va1 = *(const f32x4*)(src + p0s * 8 + 4);
    va2 = *(const f32x4*)(src + p1s * 8);
    va3 = *(const f32x4*)(src + p1s * 8 + 4);
  };
  auto AWRITE = [&](int buf) {
    s16x8 o0, o1;
#pragma unroll
    for (int e = 0; e < 4; ++e) {
      o0[e] = (short)f2bf(va0[e]);
      o0[e + 4] = (short)f2bf(va1[e]);
      o1[e] = (short)f2bf(va2[e]);
      o1[e + 4] = (short)f2bf(va3[e]);
    }
    unsigned short* d = smem + buf * 4096 + t * 16;
    *(s16x8*)d = o0;
    *(s16x8*)(d + 8) = o1;
  };
  auto STAGEB = [&](int kt, int buf) {
    char* dbase = (char*)(smem + 8192 + buf * 4096);
    gload_lds16(Bt + (size_t)(n0 + br) * 256 + kt * 32 + bsl * 8, dbase + t * 16);
    gload_lds16(Bt + (size_t)(n0 + 64 + br) * 256 + kt * 32 + bsl * 8,
                dbase + 4096 + t * 16);
  };

  f32x4 acc[4][4];
#pragma unroll
  for (int i = 0; i < 4; ++i)
#pragma unroll
    for (int j = 0; j < 4; ++j) acc[i][j] = f32x4{0.f, 0.f, 0.f, 0.f};

  const int fsl = (lg ^ (lr & 3)) * 8;

  ALOAD(0);
  STAGEB(0, 0);
  asm volatile("s_waitcnt vmcnt(0)" ::: "memory");
  AWRITE(0);
  LDSBAR();

#pragma unroll
  for (int kt = 0; kt < 8; ++kt) {
    const int cur = kt & 1;
    if (kt < 7) {
      ALOAD(kt + 1);
      STAGEB(kt + 1, cur ^ 1);
    }
    bf16x8 af[4], bfv[4];
#pragma unroll
    for (int j = 0; j < 4; ++j)
      bfv[j] = *(const bf16x8*)&smem[8192 + cur * 4096 + (wc * 64 + j * 16 + lr) * 32 + fsl];
#pragma unroll
    for (int i = 0; i < 4; ++i)
      af[i] = *(const bf16x8*)&smem[cur * 4096 + (wr * 64 + i * 16 + lr) * 32 + fsl];
    __builtin_amdgcn_s_setprio(1);
#pragma unroll
    for (int i = 0; i < 4; ++i)
#pragma unroll
      for (int j = 0; j < 4; ++j)
        acc[i][j] = __builtin_amdgcn_mfma_f32_16x16x32_bf16(af[i], bfv[j], acc[i][j], 0, 0, 0);
    __builtin_amdgcn_s_setprio(0);
    if (kt < 7) {
      asm volatile("s_waitcnt vmcnt(0)" ::: "memory");
      AWRITE(cur ^ 1);
    }
    LDSBAR();
  }

  // epilogue: 2 chunks of 64 rows via LDS, coalesced stores
  unsigned short* dstp = (n0 < 256) ? q : (n0 < 512 ? k : v);
  const int cbase = n0 & 255;
  unsigned short* eph = smem;  // [64][136]
#pragma unroll
  for (int c = 0; c < 2; ++c) {
    if (c) LDSBAR();
    if (wr == c) {
#pragma unroll
      for (int i = 0; i < 4; ++i) {
        const int lbase = i * 16 + lg * 4;
#pragma unroll
        for (int j = 0; j < 4; ++j) {
          const int col = wc * 64 + j * 16 + lr;
#pragma unroll
          for (int r2 = 0; r2 < 4; ++r2) eph[(lbase + r2) * 136 + col] = f2bf(acc[i][j][r2]);
        }
      }
    }
    LDSBAR();
#pragma unroll
    for (int c2 = 0; c2 < 4; ++c2) {
      const int lrow = c2 * 16 + (t >> 4);
      const s16x8 vv = *(const s16x8*)&eph[lrow * 136 + (t & 15) * 8];
      *(s16x8*)&dstp[(size_t)(m0 + c * 64 + lrow) * C + cbase + (t & 15) * 8] = vv;
    }
  }
}

// ================ 128x128 BK32 4-wave GEMM: proj (A = v*memb, out=f32+bias+y2) ==========
__global__ __launch_bounds__(256) void gemm128_proj_kernel(
    const unsigned short* __restrict__ V, const unsigned short* __restrict__ memb,
    const unsigned short* __restrict__ weff, const float* __restrict__ bias,
    const unsigned short* __restrict__ y2, float* __restrict__ out) {
  __shared__ alignas(16) unsigned short smem[16384];  // 32KB
  const int nwg = gridDim.x;
  const int bid = blockIdx.x;
  const int qd = nwg >> 3, rr = nwg & 7;
  const int xcd = bid & 7, sidx = bid >> 3;
  const int swz = (xcd < rr ? xcd * (qd + 1) : rr * (qd + 1) + (xcd - rr) * qd) + sidx;
  const int m0 = (swz >> 1) * 128;
  const int n0 = (swz & 1) * 128;
  const unsigned short* Bt = weff + (size_t)(m0 >> 14) * 65536;  // per-batch Weff
  const int t = threadIdx.x;
  const int w = t >> 6, l = t & 63;
  const int wr = w >> 1, wc = w & 1;
  const int lr = l & 15, lg = l >> 4;

  const int r = t >> 1;
  const int rm3 = r & 3;
  const int p0s = (((t & 1) * 2 + 0) ^ rm3);
  const int p1s = (((t & 1) * 2 + 1) ^ rm3);
  const size_t mrow = (size_t)((m0 & 16383) + r);
  const int br = t >> 2;
  const int bsl = (t & 3) ^ (br & 3);

  s16x8 va0, va1, ma0, ma1;
  auto ALOAD = [&](int kt) {
    const unsigned short* vsrc = V + (size_t)(m0 + r) * 256 + kt * 32;
    const unsigned short* msrc = memb + mrow * 256 + kt * 32;
    va0 = *(const s16x8*)(vsrc + p0s * 8);
    ma0 = *(const s16x8*)(msrc + p0s * 8);
    va1 = *(const s16x8*)(vsrc + p1s * 8);
    ma1 = *(const s16x8*)(msrc + p1s * 8);
  };
  auto AWRITE = [&](int buf) {
    s16x8 o0, o1;
#pragma unroll
    for (int e = 0; e < 8; ++e) {
      o0[e] = (short)f2bf(bf2f((unsigned short)va0[e]) * bf2f((unsigned short)ma0[e]));
      o1[e] = (short)f2bf(bf2f((unsigned short)va1[e]) * bf2f((unsigned short)ma1[e]));
    }
    unsigned short* d = smem + buf * 4096 + t * 16;
    *(s16x8*)d = o0;
    *(s16x8*)(d + 8) = o1;
  };
  auto STAGEB = [&](int kt, int buf) {
    char* dbase = (char*)(smem + 8192 + buf * 4096);
    gload_lds16(Bt + (size_t)(n0 + br) * 256 + kt * 32 + bsl * 8, dbase + t * 16);
    gload_lds16(Bt + (size_t)(n0 + 64 + br) * 256 + kt * 32 + bsl * 8,
                dbase + 4096 + t * 16);
  };

  f32x4 acc[4][4];
#pragma unroll
  for (int i = 0; i < 4; ++i)
#pragma unroll
    for (int j = 0; j < 4; ++j) acc[i][j] = f32x4{0.f, 0.f, 0.f, 0.f};

  const int fsl = (lg ^ (lr & 3)) * 8;

  ALOAD(0);
  STAGEB(0, 0);
  asm volatile("s_waitcnt vmcnt(0)" ::: "memory");
  AWRITE(0);
  LDSBAR();

#pragma unroll
  for (int kt = 0; kt < 8; ++kt) {
    const int cur = kt & 1;
    if (kt < 7) {
      ALOAD(kt + 1);
      STAGEB(kt + 1, cur ^ 1);
    }
    bf16x8 af[4], bfv[4];
#pragma unroll
    for (int j = 0; j < 4; ++j)
      bfv[j] = *(const bf16x8*)&smem[8192 + cur * 4096 + (wc * 64 + j * 16 + lr) * 32 + fsl];
#pragma unroll
    for (int i = 0; i < 4; ++i)
      af[i] = *(const bf16x8*)&smem[cur * 4096 + (wr * 64 + i * 16 + lr) * 32 + fsl];
    __builtin_amdgcn_s_setprio(1);
#pragma unroll
    for (int i = 0; i < 4; ++i)
#pragma unroll
      for (int j = 0; j < 4; ++j)
        acc[i][j] = __builtin_amdgcn_mfma_f32_16x16x32_bf16(af[i], bfv[j], acc[i][j], 0, 0, 0);
    __builtin_amdgcn_s_setprio(0);
    if (kt < 7) {
      asm volatile("s_waitcnt vmcnt(0)" ::: "memory");
      AWRITE(cur ^ 1);
    }
    LDSBAR();
  }

  // f32 epilogue: out = acc + bias + y2 ; 4 chunks of 32 rows
  float* ephf = (float*)smem;  // [32][132]
  const int colc = t & 31;
  const int trow = t >> 5;
  const int gc4 = n0 + colc * 4;
  const f32x4 bv = *(const f32x4*)&bias[gc4];
#pragma unroll
  for (int c = 0; c < 4; ++c) {
    if (c) LDSBAR();
    if (wr == (c >> 1)) {
#pragma unroll
      for (int b2 = 0; b2 < 2; ++b2) {
        const int ii = (c & 1) * 2 + b2;
        const int lbase = b2 * 16 + lg * 4;
#pragma unroll
        for (int j = 0; j < 4; ++j) {
          const int col = wc * 64 + j * 16 + lr;
#pragma unroll
          for (int r2 = 0; r2 < 4; ++r2) ephf[(lbase + r2) * 132 + col] = acc[ii][j][r2];
        }
      }
    }
    LDSBAR();
#pragma unroll
    for (int c2 = 0; c2 < 4; ++c2) {
      const int lrow = c2 * 8 + trow;
      const int grow = m0 + c * 32 + lrow;
      const f32x4 vv = *(const f32x4*)&ephf[lrow * 132 + colc * 4];
      const s16x4 yv = *(const s16x4*)&y2[(size_t)grow * C + gc4];
      f32x4 o;
#pragma unroll
      for (int e = 0; e < 4; ++e) o[e] = vv[e] + bv[e] + bf2f((unsigned short)yv[e]);
      *(f32x4*)&out[(size_t)grow * C + gc4] = o;
    }
  }
}

// ---------------- 2-phase 128x128 GEMM (small mask GEMMs) ----------------
__global__ __launch_bounds__(256) void gemm_bt_kernel(
    const unsigned short* __restrict__ A, const unsigned short* __restrict__ Bt, const int K,
    const int nbn, const int mode, unsigned short* __restrict__ ob0,
    unsigned short* __restrict__ ob1, unsigned short* __restrict__ ob2,
    const float* __restrict__ bias, float* __restrict__ of32) {
  __shared__ unsigned short lA[2][128 * 64];
  __shared__ unsigned short lB[2][128 * 64];
  const int nwg = gridDim.x;
  const int bid = blockIdx.x;
  const int qd = nwg >> 3, rr = nwg & 7;
  const int xcd = bid & 7, sidx = bid >> 3;
  const int swz = (xcd < rr ? xcd * (qd + 1) : rr * (qd + 1) + (xcd - rr) * qd) + sidx;
  const int m0 = (swz / nbn) * 128;
  const int n0 = (swz % nbn) * 128;
  const int t = threadIdx.x;
  const int w = t >> 6, l = t & 63;
  const int wr = w >> 1, wc = w & 1;
  const int lr = l & 15, lg = l >> 4;

  const int strow = (l >> 3);
  const int scolb = (((l & 7) ^ strow) << 4);

  f32x4 acc[4][4];
#pragma unroll
  for (int i = 0; i < 4; ++i)
#pragma unroll
    for (int j = 0; j < 4; ++j) acc[i][j] = f32x4{0.f, 0.f, 0.f, 0.f};

  auto stage = [&](int buf, int k0) {
#pragma unroll
    for (int s = 0; s < 4; ++s) {
      const int seg = w * 4 + s;
      const int row = seg * 8 + strow;
      gload_lds16((const char*)A + ((size_t)(m0 + row) * K + k0) * 2 + scolb,
                  (char*)&lA[buf][0] + seg * 1024 + (l & 7) * 16);
      gload_lds16((const char*)Bt + ((size_t)(n0 + row) * K + k0) * 2 + scolb,
                  (char*)&lB[buf][0] + seg * 1024 + (l & 7) * 16);
    }
  };
  auto compute = [&](int buf) {
#pragma unroll
    for (int kk = 0; kk < 64; kk += 32) {
      bf16x8 af[4], bfr[4];
      const int sbase = (kk >> 3) + lg;
      const int p = (sbase ^ (lr & 7)) << 3;
#pragma unroll
      for (int i = 0; i < 4; ++i)
        af[i] = *(const bf16x8*)&lA[buf][(wr * 64 + i * 16 + lr) * 64 + p];
#pragma unroll
      for (int j = 0; j < 4; ++j)
        bfr[j] = *(const bf16x8*)&lB[buf][(wc * 64 + j * 16 + lr) * 64 + p];
#pragma unroll
      for (int i = 0; i < 4; ++i)
#pragma unroll
        for (int j = 0; j < 4; ++j)
          acc[i][j] = __builtin_amdgcn_mfma_f32_16x16x32_bf16(af[i], bfr[j], acc[i][j], 0, 0, 0);
    }
  };

  stage(0, 0);
  __syncthreads();
  int cur = 0;
  for (int k0 = 64; k0 < K; k0 += 64) {
    stage(cur ^ 1, k0);
    compute(cur);
    __syncthreads();
    cur ^= 1;
  }
  compute(cur);

#pragma unroll
  for (int i = 0; i < 4; ++i) {
    const int grow = m0 + wr * 64 + i * 16 + lg * 4;
#pragma unroll
    for (int j = 0; j < 4; ++j) {
      const int gcol = n0 + wc * 64 + j * 16 + lr;
#pragma unroll
      for (int r = 0; r < 4; ++r) {
        const float v = acc[i][j][r];
        const size_t row = (size_t)(grow + r);
        if (mode == 0) {
          unsigned short* dst = (gcol < 256) ? ob0 : (gcol < 512 ? ob1 : ob2);
          dst[row * C + (gcol & 255)] = f2bf(v);
        } else if (mode == 1) {
          ob0[row * C + gcol] = f2bf(v + bias[gcol]);
        } else {
          const size_t idx = row * C + gcol;
          of32[idx] += v + bias[gcol];
        }
      }
    }
  }
}

// ---------------- depthwise 5x5 + sigmoid + mask_emb ----------------
__global__ __launch_bounds__(256) void mask_dw5_kernel(
    const unsigned short* __restrict__ m2, const unsigned short* __restrict__ m1,
    const float* __restrict__ dw, const float* __restrict__ db,
    unsigned short* __restrict__ memb) {
  __shared__ float wlds[25 * 256];
  __shared__ float blds[256];
  const int t = threadIdx.x;
  const int y = blockIdx.y;
  const int x0 = blockIdx.x * 16 + (t >> 6) * 4;
  const int cg = (t & 63) * 4;
#pragma unroll
  for (int e = 0; e < 25; ++e) wlds[e * 256 + t] = dw[t * 25 + e];
  blds[t] = db[t];
  __syncthreads();

  const f32x4 bias = *(const f32x4*)&blds[cg];
  f32x4 acc[4];
#pragma unroll
  for (int xi = 0; xi < 4; ++xi) acc[xi] = bias;

#pragma unroll
  for (int dy = 0; dy < 5; ++dy) {
    const int yy = y + dy - 2;
    if (yy < 0 || yy >= HW) continue;
    f32x4 col[8];
#pragma unroll
    for (int j = 0; j < 8; ++j) {
      const int xx = x0 - 2 + j;
      if (xx >= 0 && xx < HW) {
        const s16x4 v = *(const s16x4*)&m2[((size_t)yy * HW + xx) * C + cg];
        col[j][0] = bf2f((unsigned short)v[0]);
        col[j][1] = bf2f((unsigned short)v[1]);
        col[j][2] = bf2f((unsigned short)v[2]);
        col[j][3] = bf2f((unsigned short)v[3]);
      } else {
        col[j] = f32x4{0.f, 0.f, 0.f, 0.f};
      }
    }
#pragma unroll
    for (int dx = 0; dx < 5; ++dx) {
      const f32x4 wv = *(const f32x4*)&wlds[(dy * 5 + dx) * 256 + cg];
#pragma unroll
      for (int xi = 0; xi < 4; ++xi) acc[xi] += wv * col[dx + xi];
    }
  }

#pragma unroll
  for (int xi = 0; xi < 4; ++xi) {
    const size_t oi = ((size_t)y * HW + x0 + xi) * C + cg;
    const s16x4 mv = *(const s16x4*)&m1[oi];
    s16x4 o;
#pragma unroll
    for (int ch = 0; ch < 4; ++ch) {
      const float a = 1.f / (1.f + __expf(-acc[xi][ch]));
      o[ch] = (short)f2bf(bf2f((unsigned short)mv[ch]) * (1.f + a));
    }
    *(s16x4*)&memb[oi] = o;
  }
}

// ---------------- Gram partials + fused sumsq (f32 LDS staging) ----------------
__global__ __launch_bounds__(256) void gram_kernel(const unsigned short* __restrict__ qb,
                                                   const unsigned short* __restrict__ kb,
                                                   float* __restrict__ Gpart,
                                                   float* __restrict__ ssq,
                                                   float* __restrict__ ssk) {
  const int chunk = blockIdx.x;  // 16
  const int h = blockIdx.y;      // 8
  const int b = blockIdx.z;      // 4
  __shared__ float flk[128 * 32], flq[128 * 32];
  const int t = threadIdx.x;
  const int wv = t >> 6;
  const int i0 = (t & 7) * 4, j0 = ((t >> 3) & 7) * 4;
  const int lrow = t >> 2, lcb = (t & 3) * 8;
  float acc[4][4] = {};
  float sq[8] = {}, sk[8] = {};
  for (int sub = 0; sub < 8; ++sub) {
    const size_t nbase = (size_t)b * NTOK + chunk * 1024 + sub * 128;
    __syncthreads();
#pragma unroll
    for (int it = 0; it < 2; ++it) {
      const int row = it * 64 + lrow;
      const s16x8 kv8 = *(const s16x8*)&kb[(nbase + row) * C + h * 32 + lcb];
      const s16x8 qv8 = *(const s16x8*)&qb[(nbase + row) * C + h * 32 + lcb];
      f32x4 ka, kbb, qa, qbb;
#pragma unroll
      for (int e = 0; e < 4; ++e) {
        ka[e] = bf2f((unsigned short)kv8[e]);
        kbb[e] = bf2f((unsigned short)kv8[e + 4]);
        qa[e] = bf2f((unsigned short)qv8[e]);
        qbb[e] = bf2f((unsigned short)qv8[e + 4]);
      }
#pragma unroll
      for (int e = 0; e < 4; ++e) {
        sk[e] += ka[e] * ka[e];
        sk[e + 4] += kbb[e] * kbb[e];
        sq[e] += qa[e] * qa[e];
        sq[e + 4] += qbb[e] * qbb[e];
      }
      *(f32x4*)&flk[row * 32 + lcb] = ka;
      *(f32x4*)&flk[row * 32 + lcb + 4] = kbb;
      *(f32x4*)&flq[row * 32 + lcb] = qa;
      *(f32x4*)&flq[row * 32 + lcb + 4] = qbb;
    }
    __syncthreads();
    for (int n = wv; n < 128; n += 4) {
      const f32x4 kv = *(const f32x4*)&flk[n * 32 + i0];
      const f32x4 qv = *(const f32x4*)&flq[n * 32 + j0];
#pragma unroll
      for (int a = 0; a < 4; ++a)
#pragma unroll
        for (int bb = 0; bb < 4; ++bb) acc[a][bb] += kv[a] * qv[bb];
    }
  }
  const int pc = chunk * 4 + wv;
  float* dst = Gpart + (((size_t)pc * B + b) * HEADS + h) * 1024;
#pragma unroll
  for (int a = 0; a < 4; ++a)
#pragma unroll
    for (int bb = 0; bb < 4; ++bb) dst[(i0 + a) * 32 + (j0 + bb)] = acc[a][bb];
  __syncthreads();
#pragma unroll
  for (int e = 0; e < 8; ++e) {
    flq[t * 8 + e] = sq[e];
    flk[t * 8 + e] = sk[e];
  }
  __syncthreads();
  if (t < 32) {
    const int tm = t >> 3, e = t & 7;
    float s1 = 0.f, s2 = 0.f;
    for (int k2 = 0; k2 < 64; ++k2) {
      const int tt = tm + k2 * 4;
      s1 += flq[tt * 8 + e];
      s2 += flk[tt * 8 + e];
    }
    ssq[((size_t)b * 16 + chunk) * C + h * 32 + t] = s1;
    ssk[((size_t)b * 16 + chunk) * C + h * 32 + t] = s2;
  }
}

// ---------------- reduce + normalize + softmax -> attn bf16 ----------------
__global__ __launch_bounds__(256) void softmax_kernel(
    const float* __restrict__ Gpart, const float* __restrict__ ssq,
    const float* __restrict__ ssk, const float* __restrict__ rescale,
    unsigned short* __restrict__ attnb) {
  const int h = blockIdx.x, b = blockIdx.y;
  const int t = threadIdx.x;
  __shared__ float G[1024];
  __shared__ float nq[32], nk[32];
#pragma unroll
  for (int e = 0; e < 4; ++e) {
    const int cell = e * 256 + t;
    float s = 0.f;
    for (int pc = 0; pc < 64; ++pc)
      s += Gpart[(((size_t)pc * B + b) * HEADS + h) * 1024 + cell];
    G[cell] = s;
  }
  if (t < 64) {
    const int d = t & 31;
    const float* ss = (t < 32) ? ssq : ssk;
    float s = 0.f;
    for (int ch = 0; ch < 16; ++ch) s += ss[((size_t)b * 16 + ch) * C + h * 32 + d];
    const float nn = fmaxf(sqrtf(s), 1e-12f);
    if (t < 32) nq[d] = nn;
    else nk[d] = nn;
  }
  __syncthreads();
  if (t < 32) {
    const int i = t;
    const float rs = rescale[h];
    float row[32];
    float mx = -1e30f;
#pragma unroll
    for (int j = 0; j < 32; ++j) {
      const float v = G[i * 32 + j] / (nk[i] * nq[j]) * rs;
      row[j] = v;
      mx = fmaxf(mx, v);
    }
    float sum = 0.f;
#pragma unroll
    for (int j = 0; j < 32; ++j) {
      const float e = expf(row[j] - mx);
      row[j] = e;
      sum += e;
    }
    const float inv = 1.f / sum;
#pragma unroll
    for (int j = 0; j < 32; ++j)
      attnb[(((size_t)b * HEADS + h) * 32 + i) * 32 + j] = f2bf(row[j] * inv);
  }
}

// ---------------- Weff[b][o][32h+j] = sum_i attn[b,h,i,j] * wprojT[o][32h+i] ------------
__global__ __launch_bounds__(256) void weff_kernel(const unsigned short* __restrict__ attnb,
                                                   const unsigned short* __restrict__ wprojT,
                                                   unsigned short* __restrict__ weff) {
  const int b = blockIdx.y;
  const int co0 = blockIdx.x * 64;
  const int t = threadIdx.x;
  __shared__ float att[8192];
  for (int e = t; e < 8192; e += 256) att[e] = bf2f(attnb[(size_t)b * 8192 + e]);
  __syncthreads();
  const int o = co0 + (t & 63);
  const int hq = t >> 6;
#pragma unroll
  for (int hh = 0; hh < 2; ++hh) {
    const int h = hq * 2 + hh;
    float wp[32];
#pragma unroll
    for (int i = 0; i < 32; ++i) wp[i] = bf2f(wprojT[(size_t)o * 256 + h * 32 + i]);
    for (int j4 = 0; j4 < 8; ++j4) {
      f32x4 s = {0.f, 0.f, 0.f, 0.f};
#pragma unroll
      for (int i = 0; i < 32; ++i) {
        const f32x4 a4 = *(const f32x4*)&att[(h * 32 + i) * 32 + j4 * 4];
        s += wp[i] * a4;
      }
      s16x4 oo;
#pragma unroll
      for (int e = 0; e < 4; ++e) oo[e] = (short)f2bf(s[e]);
      *(s16x4*)&weff[((size_t)b * 256 + o) * 256 + h * 32 + j4 * 4] = oo;
    }
  }
}

// ---------------- depthwise 3x3, 4 channels/thread ----------------
__global__ __launch_bounds__(512) void dw3_kernel(const unsigned short* __restrict__ in,
                                                  const float* __restrict__ wgt,
                                                  unsigned short* __restrict__ out_bf,
                                                  const int do_gelu) {
  const int y = blockIdx.x;
  const int b = blockIdx.y;
  const int t = threadIdx.x;
  const int cg = (t & 63) * 4;
  const int x0 = (t >> 6) * 16;
  float w[9][4];
#pragma unroll
  for (int e = 0; e < 9; ++e)
#pragma unroll
    for (int ch = 0; ch < 4; ++ch) w[e][ch] = wgt[(cg + ch) * 9 + e];
  const int ym = y - 1, yp = y + 1;
  const bool hm = (ym >= 0), hp = (yp < HW);
  const size_t base = (size_t)b * NTOK * C + cg;
  auto ld4 = [&](int yy, int xx) -> f32x4 {
    const s16x4 v = *(const s16x4*)&in[base + ((size_t)yy * HW + xx) * C];
    f32x4 f;
    f[0] = bf2f((unsigned short)v[0]);
    f[1] = bf2f((unsigned short)v[1]);
    f[2] = bf2f((unsigned short)v[2]);
    f[3] = bf2f((unsigned short)v[3]);
    return f;
  };
  const f32x4 zero = {0.f, 0.f, 0.f, 0.f};
  f32x4 a0, a1, a2, b0, b1, b2;
  if (x0 > 0) {
    a0 = hm ? ld4(ym, x0 - 1) : zero;
    a1 = ld4(y, x0 - 1);
    a2 = hp ? ld4(yp, x0 - 1) : zero;
  } else {
    a0 = a1 = a2 = zero;
  }
  b0 = hm ? ld4(ym, x0) : zero;
  b1 = ld4(y, x0);
  b2 = hp ? ld4(yp, x0) : zero;
  for (int xi = 0; xi < 16; ++xi) {
    const int x = x0 + xi;
    f32x4 c0, c1, c2;
    if (x + 1 < HW) {
      c0 = hm ? ld4(ym, x + 1) : zero;
      c1 = ld4(y, x + 1);
      c2 = hp ? ld4(yp, x + 1) : zero;
    } else {
      c0 = c1 = c2 = zero;
    }
    float res[4];
#pragma unroll
    for (int ch = 0; ch < 4; ++ch) {
      float r = w[0][ch] * a0[ch] + w[1][ch] * b0[ch] + w[2][ch] * c0[ch] +
                w[3][ch] * a1[ch] + w[4][ch] * b1[ch] + w[5][ch] * c1[ch] +
                w[6][ch] * a2[ch] + w[7][ch] * b2[ch] + w[8][ch] * c2[ch];
      if (do_gelu) r = 0.5f * r * (1.f + erff(r * 0.70710678118654752f));
      res[ch] = r;
    }
    const size_t oi = base + ((size_t)y * HW + x) * C;
    s16x4 o;
    o[0] = (short)f2bf(res[0]);
    o[1] = (short)f2bf(res[1]);
    o[2] = (short)f2bf(res[2]);
    o[3] = (short)f2bf(res[3]);
    *(s16x4*)&out_bf[oi] = o;
    a0 = b0; a1 = b1; a2 = b2;
    b0 = c0; b1 = c1; b2 = c2;
  }
}

extern "C" void kernel_launch(void* const* d_in, const int* in_sizes, int n_in, void* d_out,
                              int out_size, void* d_ws, size_t ws_size, hipStream_t stream) {
  (void)in_sizes; (void)n_in; (void)out_size; (void)ws_size;
  const float* x = (const float*)d_in[0];
  const float* maskp = (const float*)d_in[1];
  const float* wq = (const float*)d_in[2];
  const float* wk = (const float*)d_in[3];
  const float* wv = (const float*)d_in[4];
  const float* rescale = (const float*)d_in[5];
  const float* wproj = (const float*)d_in[6];
  const float* bproj = (const float*)d_in[7];
  const float* mg_w1 = (const float*)d_in[8];
  const float* mg_b1 = (const float*)d_in[9];
  const float* mg_w2 = (const float*)d_in[10];
  const float* mg_b2 = (const float*)d_in[11];
  const float* mg_dw = (const float*)d_in[12];
  const float* mg_db = (const float*)d_in[13];
  const float* be_w1 = (const float*)d_in[14];
  const float* be_w2 = (const float*)d_in[15];
  float* out = (float*)d_out;
  char* ws = (char*)d_ws;

  unsigned short* qb = (unsigned short*)(ws + 33554432ull);     // 32MB, later y1
  unsigned short* kb = (unsigned short*)(ws + 67108864ull);     // 32MB, later y2
  unsigned short* vb = (unsigned short*)(ws + 100663296ull);    // 32MB
  unsigned short* mT = (unsigned short*)(ws + 134217728ull);    // 8MB, later mask_emb
  unsigned short* m1b = (unsigned short*)(ws + 142606336ull);   // 8MB, later Weff
  unsigned short* m2b = (unsigned short*)(ws + 150994944ull);   // 8MB, later Gpart
  unsigned short* wqkvT = (unsigned short*)(ws + 159383552ull); // 384KB
  unsigned short* wprojT = (unsigned short*)(ws + 159776768ull);// 128KB
  unsigned short* w1b = (unsigned short*)(ws + 159907840ull);   // 128KB
  unsigned short* w2b = (unsigned short*)(ws + 160038912ull);   // 128KB
  float* ssq = (float*)(ws + 160169984ull);                     // 64KB
  float* ssk = (float*)(ws + 160432128ull);                     // 64KB
  unsigned short* attnb = (unsigned short*)(ws + 160694272ull); // 64KB
  float* Gpart = (float*)m2b;
  unsigned short* memb = mT;
  unsigned short* y1 = qb;
  unsigned short* y2 = kb;
  unsigned short* weff = m1b;

  prep_w_kernel<<<dim3(256, 6), 256, 0, stream>>>(wq, wk, wv, wproj, mg_w1, mg_w2, wqkvT,
                                                  wprojT, w1b, w2b);
  tmask_kernel<<<dim3(512, 8), 1024, 0, stream>>>(maskp, mT);
  // mask branch
  gemm_bt_kernel<<<256, 256, 0, stream>>>(mT, w1b, 256, 2, 1, m1b, nullptr, nullptr, mg_b1,
                                          nullptr);
  gemm_bt_kernel<<<256, 256, 0, stream>>>(m1b, w2b, 256, 2, 1, m2b, nullptr, nullptr, mg_b2,
                                          nullptr);
  mask_dw5_kernel<<<dim3(8, 128), 256, 0, stream>>>(m2b, m1b, mg_dw, mg_db, memb);
  // q,k,v straight from f32 x (cast fused into staging)
  gemm128_qkv_kernel<<<3072, 256, 0, stream>>>(x, wqkvT, qb, kb, vb);
  gram_kernel<<<dim3(16, 8, 4), 256, 0, stream>>>(qb, kb, Gpart, ssq, ssk);
  softmax_kernel<<<dim3(8, 4), 256, 0, stream>>>(Gpart, ssq, ssk, rescale, attnb);
  weff_kernel<<<dim3(4, 4), 256, 0, stream>>>(attnb, wprojT, weff);
  // band branch: y1 = gelu(dw3(v)); y2 = dw3(y1)
  dw3_kernel<<<dim3(128, 4), 512, 0, stream>>>(vb, be_w1, y1, 1);
  dw3_kernel<<<dim3(128, 4), 512, 0, stream>>>(y1, be_w2, y2, 0);
  // proj: out = (v*memb) @ Weff_b^T + bproj + y2  (vma fused into staging)
  gemm128_proj_kernel<<<1024, 256, 0, stream>>>(vb, memb, weff, bproj, y2, out);
}

// Round 11
// 278.121 us; speedup vs baseline: 1.1355x; 1.1355x over previous
//
#include <hip/hip_runtime.h>
#include <stdint.h>

#define B 4
#define HW 128
#define C 256
#define NTOK 16384
#define MALL 65536
#define HEADS 8
#define DH 32

typedef float f32x4 __attribute__((ext_vector_type(4)));
typedef short s16x8 __attribute__((ext_vector_type(8)));
typedef short s16x4 __attribute__((ext_vector_type(4)));
typedef __bf16 bf16x8 __attribute__((ext_vector_type(8)));

__device__ __forceinline__ float bf2f(unsigned short u) {
  union { unsigned int i; float f; } x;
  x.i = ((unsigned int)u) << 16;
  return x.f;
}
__device__ __forceinline__ unsigned short f2bf(float f) {
  union { float f; unsigned int i; } x;
  x.f = f;
  unsigned int lsb = (x.i >> 16) & 1u;
  unsigned int r = x.i + 0x7fffu + lsb;
  return (unsigned short)(r >> 16);
}

__device__ __forceinline__ void gload_lds16(const void* g, void* l) {
  auto gp = reinterpret_cast<const __attribute__((address_space(1))) unsigned int*>(
      reinterpret_cast<uintptr_t>(g));
  auto lp = reinterpret_cast<__attribute__((address_space(3))) unsigned int*>(
      reinterpret_cast<uintptr_t>(l));
  __builtin_amdgcn_global_load_lds(gp, lp, 16, 0, 0);
}

#define CFENCE asm volatile("" ::: "memory")
#define LDSBAR()                                        \
  do {                                                  \
    asm volatile("s_waitcnt lgkmcnt(0)" ::: "memory");  \
    __builtin_amdgcn_s_barrier();                       \
    CFENCE;                                             \
  } while (0)

// ---------------- weight prep: transpose+cast ----------------
__global__ __launch_bounds__(256) void prep_w_kernel(
    const float* __restrict__ wq, const float* __restrict__ wk, const float* __restrict__ wv,
    const float* __restrict__ wproj, const float* __restrict__ w1, const float* __restrict__ w2,
    unsigned short* __restrict__ wqkvT, unsigned short* __restrict__ wprojT,
    unsigned short* __restrict__ w1b, unsigned short* __restrict__ w2b) {
  const int idx = blockIdx.x * 256 + threadIdx.x;  // 0..65535
  const int mat = blockIdx.y;
  const int n = idx >> 8, k = idx & 255;
  switch (mat) {
    case 0: wqkvT[idx] = f2bf(wq[k * 256 + n]); break;
    case 1: wqkvT[65536 + idx] = f2bf(wk[k * 256 + n]); break;
    case 2: wqkvT[131072 + idx] = f2bf(wv[k * 256 + n]); break;
    case 3: wprojT[idx] = f2bf(wproj[k * 256 + n]); break;
    case 4: w1b[idx] = f2bf(w1[idx]); break;
    case 5: w2b[idx] = f2bf(w2[idx]); break;
  }
}

// ---------------- transpose mask [C][N] -> [N][C] bf16 ----------------
__global__ __launch_bounds__(1024) void tmask_kernel(const float* __restrict__ mask,
                                                     unsigned short* __restrict__ mT) {
  __shared__ float tile[32][33];
  const int p0 = blockIdx.x * 32, c0 = blockIdx.y * 32;
  const int tx = threadIdx.x & 31, ty = threadIdx.x >> 5;
  tile[ty][tx] = mask[(size_t)(c0 + ty) * NTOK + p0 + tx];
  __syncthreads();
  mT[(size_t)(p0 + ty) * C + c0 + tx] = f2bf(tile[tx][ty]);
}

// ================ 256x256 8-wave GEMM (R7 structure), A reg-staged from f32 x ===========
// qkv: C = cast(X) @ wqkvT^T, bf16 out selected by n0/256.
__global__ __launch_bounds__(512) void gemm256_qkv_kernel(
    const float* __restrict__ X, const unsigned short* __restrict__ Bt,
    unsigned short* __restrict__ q, unsigned short* __restrict__ k,
    unsigned short* __restrict__ v) {
  __shared__ alignas(16) unsigned short smem[32768];  // 64KB: lA 2x8192, lB 2x8192
  unsigned short* lAb = smem;
  unsigned short* lBb = smem + 16384;
  const int nwg = gridDim.x;
  const int bid = blockIdx.x;
  const int qd = nwg >> 3, rr = nwg & 7;
  const int xcd = bid & 7, sidx = bid >> 3;
  const int swz = (xcd < rr ? xcd * (qd + 1) : rr * (qd + 1) + (xcd - rr) * qd) + sidx;
  const int m0 = (swz / 3) * 256;
  const int n0 = (swz % 3) * 256;
  const int t = threadIdx.x;
  const int w = t >> 6, l = t & 63;
  const int wr = w >> 2, wc = w & 3;   // wave grid 2(M) x 4(N)
  const int lr = l & 15, lg = l >> 4;

  const int srow = t >> 2;
  const int ssl = (t & 3) ^ ((t >> 3) & 3);

  f32x4 va0, va1, va2, va3;
  auto ALOAD = [&](int kt) {
    const float* s0 = X + (size_t)(m0 + srow) * 256 + kt * 32 + ssl * 8;
    const float* s1 = X + (size_t)(m0 + 128 + srow) * 256 + kt * 32 + ssl * 8;
    va0 = *(const f32x4*)s0;
    va1 = *(const f32x4*)(s0 + 4);
    va2 = *(const f32x4*)s1;
    va3 = *(const f32x4*)(s1 + 4);
  };
  auto AWRITE = [&](int buf) {
    s16x8 o0, o1;
#pragma unroll
    for (int e = 0; e < 4; ++e) {
      o0[e] = (short)f2bf(va0[e]);
      o0[e + 4] = (short)f2bf(va1[e]);
      o1[e] = (short)f2bf(va2[e]);
      o1[e + 4] = (short)f2bf(va3[e]);
    }
    char* d = (char*)(lAb + buf * 8192);
    *(s16x8*)(d + t * 16) = o0;
    *(s16x8*)(d + 8192 + t * 16) = o1;
  };
  auto STAGEB = [&](int kt, int buf) {
    unsigned short* d = lBb + buf * 8192;
    const size_t kb = ((size_t)kt * 32 + ssl * 8) * 2;
    gload_lds16((const char*)Bt + ((size_t)(n0 + srow) * 256) * 2 + kb, (char*)d + t * 16);
    gload_lds16((const char*)Bt + ((size_t)(n0 + 128 + srow) * 256) * 2 + kb,
                (char*)d + 8192 + t * 16);
  };

  f32x4 acc[8][4];
#pragma unroll
  for (int m = 0; m < 8; ++m)
#pragma unroll
    for (int j = 0; j < 4; ++j) acc[m][j] = f32x4{0.f, 0.f, 0.f, 0.f};

  const int asl = (lg ^ ((lr >> 1) & 3)) * 8;
  const int aoff = lr * 32 + asl;
  const int awb = wr * 4096;
  const int boff = (wc >> 1) * 4096 + ((wc & 1) * 64 + lr) * 32 + asl;

  ALOAD(0);
  STAGEB(0, 0);
  asm volatile("s_waitcnt vmcnt(0)" ::: "memory");
  AWRITE(0);
  LDSBAR();

#pragma unroll
  for (int kt = 0; kt < 8; ++kt) {
    const int cur = kt & 1;
    const unsigned short* bufA = lAb + cur * 8192;
    const unsigned short* bufB = lBb + cur * 8192;
    bf16x8 bfr[4], af[4], af2[4];
#pragma unroll
    for (int j = 0; j < 4; ++j) bfr[j] = *(const bf16x8*)&bufB[boff + j * 512];
#pragma unroll
    for (int m = 0; m < 4; ++m) af[m] = *(const bf16x8*)&bufA[awb + aoff + m * 512];
#pragma unroll
    for (int m = 0; m < 4; ++m) af2[m] = *(const bf16x8*)&bufA[awb + aoff + (m + 4) * 512];
    if (kt < 7) {
      ALOAD(kt + 1);
      STAGEB(kt + 1, cur ^ 1);
    }
    __builtin_amdgcn_s_setprio(1);
#pragma unroll
    for (int m = 0; m < 4; ++m)
#pragma unroll
      for (int j = 0; j < 4; ++j)
        acc[m][j] = __builtin_amdgcn_mfma_f32_16x16x32_bf16(af[m], bfr[j], acc[m][j], 0, 0, 0);
#pragma unroll
    for (int m = 0; m < 4; ++m)
#pragma unroll
      for (int j = 0; j < 4; ++j)
        acc[m + 4][j] =
            __builtin_amdgcn_mfma_f32_16x16x32_bf16(af2[m], bfr[j], acc[m + 4][j], 0, 0, 0);
    __builtin_amdgcn_s_setprio(0);
    if (kt < 7) {
      asm volatile("s_waitcnt vmcnt(0)" ::: "memory");
      AWRITE(cur ^ 1);
    }
    LDSBAR();
  }

  // ---- bf16 epilogue: 4 chunks of 64 rows ----
  unsigned short* dst = (n0 < 256) ? q : (n0 < 512 ? k : v);
  unsigned short* eph = smem;  // [64][264]
#pragma unroll
  for (int c = 0; c < 4; ++c) {
    LDSBAR();
    if (wr == (c >> 1)) {
#pragma unroll
      for (int mm = 0; mm < 4; ++mm) {
        const int m = (c & 1) * 4 + mm;
        const int lrow = mm * 16 + lg * 4;
#pragma unroll
        for (int j = 0; j < 4; ++j) {
          const int col = wc * 64 + j * 16 + lr;
#pragma unroll
          for (int r = 0; r < 4; ++r) eph[(lrow + r) * 264 + col] = f2bf(acc[m][j][r]);
        }
      }
    }
    LDSBAR();
    const int col16 = t & 31;
#pragma unroll
    for (int c2 = 0; c2 < 4; ++c2) {
      const int lrow = c2 * 16 + (t >> 5);
      const int grow = m0 + c * 64 + lrow;
      const s16x8 vv = *(const s16x8*)&eph[lrow * 264 + col16 * 8];
      *(s16x8*)&dst[(size_t)grow * C + col16 * 8] = vv;
    }
  }
}

// ================ 256x256 8-wave GEMM: proj (A = v*memb staged, out=f32+bias+y2) ========
__global__ __launch_bounds__(512) void gemm256_proj_kernel(
    const unsigned short* __restrict__ V, const unsigned short* __restrict__ memb,
    const unsigned short* __restrict__ weff, const float* __restrict__ bias,
    const unsigned short* __restrict__ y2, float* __restrict__ out) {
  __shared__ alignas(16) unsigned short smem[32768];  // 64KB
  unsigned short* lAb = smem;
  unsigned short* lBb = smem + 16384;
  const int nwg = gridDim.x;
  const int bid = blockIdx.x;
  const int qd = nwg >> 3, rr = nwg & 7;
  const int xcd = bid & 7, sidx = bid >> 3;
  const int swz = (xcd < rr ? xcd * (qd + 1) : rr * (qd + 1) + (xcd - rr) * qd) + sidx;
  const int m0 = swz * 256;
  const unsigned short* Bt = weff + (size_t)(m0 >> 14) * 65536;  // per-batch Weff
  const int t = threadIdx.x;
  const int w = t >> 6, l = t & 63;
  const int wr = w >> 2, wc = w & 3;
  const int lr = l & 15, lg = l >> 4;

  const int srow = t >> 2;
  const int ssl = (t & 3) ^ ((t >> 3) & 3);
  const size_t mrow = (size_t)((m0 & 16383) + srow);

  s16x8 va0, va1, ma0, ma1;
  auto ALOAD = [&](int kt) {
    const int ko = kt * 32 + ssl * 8;
    va0 = *(const s16x8*)&V[(size_t)(m0 + srow) * 256 + ko];
    ma0 = *(const s16x8*)&memb[mrow * 256 + ko];
    va1 = *(const s16x8*)&V[(size_t)(m0 + 128 + srow) * 256 + ko];
    ma1 = *(const s16x8*)&memb[(mrow + 128) * 256 + ko];
  };
  auto AWRITE = [&](int buf) {
    s16x8 o0, o1;
#pragma unroll
    for (int e = 0; e < 8; ++e) {
      o0[e] = (short)f2bf(bf2f((unsigned short)va0[e]) * bf2f((unsigned short)ma0[e]));
      o1[e] = (short)f2bf(bf2f((unsigned short)va1[e]) * bf2f((unsigned short)ma1[e]));
    }
    char* d = (char*)(lAb + buf * 8192);
    *(s16x8*)(d + t * 16) = o0;
    *(s16x8*)(d + 8192 + t * 16) = o1;
  };
  auto STAGEB = [&](int kt, int buf) {
    unsigned short* d = lBb + buf * 8192;
    const size_t kb = ((size_t)kt * 32 + ssl * 8) * 2;
    gload_lds16((const char*)Bt + ((size_t)srow * 256) * 2 + kb, (char*)d + t * 16);
    gload_lds16((const char*)Bt + ((size_t)(128 + srow) * 256) * 2 + kb,
                (char*)d + 8192 + t * 16);
  };

  f32x4 acc[8][4];
#pragma unroll
  for (int m = 0; m < 8; ++m)
#pragma unroll
    for (int j = 0; j < 4; ++j) acc[m][j] = f32x4{0.f, 0.f, 0.f, 0.f};

  const int asl = (lg ^ ((lr >> 1) & 3)) * 8;
  const int aoff = lr * 32 + asl;
  const int awb = wr * 4096;
  const int boff = (wc >> 1) * 4096 + ((wc & 1) * 64 + lr) * 32 + asl;

  ALOAD(0);
  STAGEB(0, 0);
  asm volatile("s_waitcnt vmcnt(0)" ::: "memory");
  AWRITE(0);
  LDSBAR();

#pragma unroll
  for (int kt = 0; kt < 8; ++kt) {
    const int cur = kt & 1;
    const unsigned short* bufA = lAb + cur * 8192;
    const unsigned short* bufB = lBb + cur * 8192;
    bf16x8 bfr[4], af[4], af2[4];
#pragma unroll
    for (int j = 0; j < 4; ++j) bfr[j] = *(const bf16x8*)&bufB[boff + j * 512];
#pragma unroll
    for (int m = 0; m < 4; ++m) af[m] = *(const bf16x8*)&bufA[awb + aoff + m * 512];
#pragma unroll
    for (int m = 0; m < 4; ++m) af2[m] = *(const bf16x8*)&bufA[awb + aoff + (m + 4) * 512];
    if (kt < 7) {
      ALOAD(kt + 1);
      STAGEB(kt + 1, cur ^ 1);
    }
    __builtin_amdgcn_s_setprio(1);
#pragma unroll
    for (int m = 0; m < 4; ++m)
#pragma unroll
      for (int j = 0; j < 4; ++j)
        acc[m][j] = __builtin_amdgcn_mfma_f32_16x16x32_bf16(af[m], bfr[j], acc[m][j], 0, 0, 0);
#pragma unroll
    for (int m = 0; m < 4; ++m)
#pragma unroll
      for (int j = 0; j < 4; ++j)
        acc[m + 4][j] =
            __builtin_amdgcn_mfma_f32_16x16x32_bf16(af2[m], bfr[j], acc[m + 4][j], 0, 0, 0);
    __builtin_amdgcn_s_setprio(0);
    if (kt < 7) {
      asm volatile("s_waitcnt vmcnt(0)" ::: "memory");
      AWRITE(cur ^ 1);
    }
    LDSBAR();
  }

  // ---- f32 epilogue: out = acc + bias + y2 ; 8 chunks of 32 rows ----
  float* ephf = (float*)smem;  // [32][260]
  const int colc = t & 63;
  const f32x4 bv = *(const f32x4*)&bias[colc * 4];
#pragma unroll
  for (int c = 0; c < 8; ++c) {
    LDSBAR();
    if (wr == (c >> 2)) {
#pragma unroll
      for (int mm = 0; mm < 2; ++mm) {
        const int m = (c & 3) * 2 + mm;
        const int lrow = mm * 16 + lg * 4;
#pragma unroll
        for (int j = 0; j < 4; ++j) {
          const int col = wc * 64 + j * 16 + lr;
#pragma unroll
          for (int r = 0; r < 4; ++r) ephf[(lrow + r) * 260 + col] = acc[m][j][r];
        }
      }
    }
    LDSBAR();
#pragma unroll
    for (int c2 = 0; c2 < 4; ++c2) {
      const int lrow = c2 * 8 + (t >> 6);
      const int grow = m0 + c * 32 + lrow;
      const f32x4 vv = *(const f32x4*)&ephf[lrow * 260 + colc * 4];
      const s16x4 yv = *(const s16x4*)&y2[(size_t)grow * C + colc * 4];
      f32x4 o;
#pragma unroll
      for (int e = 0; e < 4; ++e) o[e] = vv[e] + bv[e] + bf2f((unsigned short)yv[e]);
      *(f32x4*)&out[(size_t)grow * C + colc * 4] = o;
    }
  }
}

// ---------------- 2-phase 128x128 GEMM (small mask GEMMs) ----------------
__global__ __launch_bounds__(256) void gemm_bt_kernel(
    const unsigned short* __restrict__ A, const unsigned short* __restrict__ Bt, const int K,
    const int nbn, const int mode, unsigned short* __restrict__ ob0,
    const float* __restrict__ bias) {
  __shared__ unsigned short lA[2][128 * 64];
  __shared__ unsigned short lB[2][128 * 64];
  const int nwg = gridDim.x;
  const int bid = blockIdx.x;
  const int qd = nwg >> 3, rr = nwg & 7;
  const int xcd = bid & 7, sidx = bid >> 3;
  const int swz = (xcd < rr ? xcd * (qd + 1) : rr * (qd + 1) + (xcd - rr) * qd) + sidx;
  const int m0 = (swz / nbn) * 128;
  const int n0 = (swz % nbn) * 128;
  const int t = threadIdx.x;
  const int w = t >> 6, l = t & 63;
  const int wr = w >> 1, wc = w & 1;
  const int lr = l & 15, lg = l >> 4;

  const int strow = (l >> 3);
  const int scolb = (((l & 7) ^ strow) << 4);

  f32x4 acc[4][4];
#pragma unroll
  for (int i = 0; i < 4; ++i)
#pragma unroll
    for (int j = 0; j < 4; ++j) acc[i][j] = f32x4{0.f, 0.f, 0.f, 0.f};

  auto stage = [&](int buf, int k0) {
#pragma unroll
    for (int s = 0; s < 4; ++s) {
      const int seg = w * 4 + s;
      const int row = seg * 8 + strow;
      gload_lds16((const char*)A + ((size_t)(m0 + row) * K + k0) * 2 + scolb,
                  (char*)&lA[buf][0] + seg * 1024 + (l & 7) * 16);
      gload_lds16((const char*)Bt + ((size_t)(n0 + row) * K + k0) * 2 + scolb,
                  (char*)&lB[buf][0] + seg * 1024 + (l & 7) * 16);
    }
  };
  auto compute = [&](int buf) {
#pragma unroll
    for (int kk = 0; kk < 64; kk += 32) {
      bf16x8 af[4], bfr[4];
      const int sbase = (kk >> 3) + lg;
      const int p = (sbase ^ (lr & 7)) << 3;
#pragma unroll
      for (int i = 0; i < 4; ++i)
        af[i] = *(const bf16x8*)&lA[buf][(wr * 64 + i * 16 + lr) * 64 + p];
#pragma unroll
      for (int j = 0; j < 4; ++j)
        bfr[j] = *(const bf16x8*)&lB[buf][(wc * 64 + j * 16 + lr) * 64 + p];
#pragma unroll
      for (int i = 0; i < 4; ++i)
#pragma unroll
        for (int j = 0; j < 4; ++j)
          acc[i][j] = __builtin_amdgcn_mfma_f32_16x16x32_bf16(af[i], bfr[j], acc[i][j], 0, 0, 0);
    }
  };

  stage(0, 0);
  __syncthreads();
  int cur = 0;
  for (int k0 = 64; k0 < K; k0 += 64) {
    stage(cur ^ 1, k0);
    compute(cur);
    __syncthreads();
    cur ^= 1;
  }
  compute(cur);

#pragma unroll
  for (int i = 0; i < 4; ++i) {
    const int grow = m0 + wr * 64 + i * 16 + lg * 4;
#pragma unroll
    for (int j = 0; j < 4; ++j) {
      const int gcol = n0 + wc * 64 + j * 16 + lr;
#pragma unroll
      for (int r = 0; r < 4; ++r) {
        const float v = acc[i][j][r];
        const size_t row = (size_t)(grow + r);
        ob0[row * C + gcol] = f2bf(v + bias[gcol]);
      }
    }
  }
}

// ---------------- depthwise 5x5 + sigmoid + mask_emb ----------------
__global__ __launch_bounds__(256) void mask_dw5_kernel(
    const unsigned short* __restrict__ m2, const unsigned short* __restrict__ m1,
    const float* __restrict__ dw, const float* __restrict__ db,
    unsigned short* __restrict__ memb) {
  __shared__ float wlds[25 * 256];
  __shared__ float blds[256];
  const int t = threadIdx.x;
  const int y = blockIdx.y;
  const int x0 = blockIdx.x * 16 + (t >> 6) * 4;
  const int cg = (t & 63) * 4;
#pragma unroll
  for (int e = 0; e < 25; ++e) wlds[e * 256 + t] = dw[t * 25 + e];
  blds[t] = db[t];
  __syncthreads();

  const f32x4 bias = *(const f32x4*)&blds[cg];
  f32x4 acc[4];
#pragma unroll
  for (int xi = 0; xi < 4; ++xi) acc[xi] = bias;

#pragma unroll
  for (int dy = 0; dy < 5; ++dy) {
    const int yy = y + dy - 2;
    if (yy < 0 || yy >= HW) continue;
    f32x4 col[8];
#pragma unroll
    for (int j = 0; j < 8; ++j) {
      const int xx = x0 - 2 + j;
      if (xx >= 0 && xx < HW) {
        const s16x4 v = *(const s16x4*)&m2[((size_t)yy * HW + xx) * C + cg];
        col[j][0] = bf2f((unsigned short)v[0]);
        col[j][1] = bf2f((unsigned short)v[1]);
        col[j][2] = bf2f((unsigned short)v[2]);
        col[j][3] = bf2f((unsigned short)v[3]);
      } else {
        col[j] = f32x4{0.f, 0.f, 0.f, 0.f};
      }
    }
#pragma unroll
    for (int dx = 0; dx < 5; ++dx) {
      const f32x4 wv = *(const f32x4*)&wlds[(dy * 5 + dx) * 256 + cg];
#pragma unroll
      for (int xi = 0; xi < 4; ++xi) acc[xi] += wv * col[dx + xi];
    }
  }

#pragma unroll
  for (int xi = 0; xi < 4; ++xi) {
    const size_t oi = ((size_t)y * HW + x0 + xi) * C + cg;
    const s16x4 mv = *(const s16x4*)&m1[oi];
    s16x4 o;
#pragma unroll
    for (int ch = 0; ch < 4; ++ch) {
      const float a = 1.f / (1.f + __expf(-acc[xi][ch]));
      o[ch] = (short)f2bf(bf2f((unsigned short)mv[ch]) * (1.f + a));
    }
    *(s16x4*)&memb[oi] = o;
  }
}

// ---------------- Gram partials + fused sumsq (f32 LDS staging) ----------------
__global__ __launch_bounds__(256) void gram_kernel(const unsigned short* __restrict__ qb,
                                                   const unsigned short* __restrict__ kb,
                                                   float* __restrict__ Gpart,
                                                   float* __restrict__ ssq,
                                                   float* __restrict__ ssk) {
  const int chunk = blockIdx.x;  // 16
  const int h = blockIdx.y;      // 8
  const int b = blockIdx.z;      // 4
  __shared__ float flk[128 * 32], flq[128 * 32];
  const int t = threadIdx.x;
  const int wv = t >> 6;
  const int i0 = (t & 7) * 4, j0 = ((t >> 3) & 7) * 4;
  const int lrow = t >> 2, lcb = (t & 3) * 8;
  float acc[4][4] = {};
  float sq[8] = {}, sk[8] = {};
  for (int sub = 0; sub < 8; ++sub) {
    const size_t nbase = (size_t)b * NTOK + chunk * 1024 + sub * 128;
    __syncthreads();
#pragma unroll
    for (int it = 0; it < 2; ++it) {
      const int row = it * 64 + lrow;
      const s16x8 kv8 = *(const s16x8*)&kb[(nbase + row) * C + h * 32 + lcb];
      const s16x8 qv8 = *(const s16x8*)&qb[(nbase + row) * C + h * 32 + lcb];
      f32x4 ka, kbb, qa, qbb;
#pragma unroll
      for (int e = 0; e < 4; ++e) {
        ka[e] = bf2f((unsigned short)kv8[e]);
        kbb[e] = bf2f((unsigned short)kv8[e + 4]);
        qa[e] = bf2f((unsigned short)qv8[e]);
        qbb[e] = bf2f((unsigned short)qv8[e + 4]);
      }
#pragma unroll
      for (int e = 0; e < 4; ++e) {
        sk[e] += ka[e] * ka[e];
        sk[e + 4] += kbb[e] * kbb[e];
        sq[e] += qa[e] * qa[e];
        sq[e + 4] += qbb[e] * qbb[e];
      }
      *(f32x4*)&flk[row * 32 + lcb] = ka;
      *(f32x4*)&flk[row * 32 + lcb + 4] = kbb;
      *(f32x4*)&flq[row * 32 + lcb] = qa;
      *(f32x4*)&flq[row * 32 + lcb + 4] = qbb;
    }
    __syncthreads();
    for (int n = wv; n < 128; n += 4) {
      const f32x4 kv = *(const f32x4*)&flk[n * 32 + i0];
      const f32x4 qv = *(const f32x4*)&flq[n * 32 + j0];
#pragma unroll
      for (int a = 0; a < 4; ++a)
#pragma unroll
        for (int bb = 0; bb < 4; ++bb) acc[a][bb] += kv[a] * qv[bb];
    }
  }
  const int pc = chunk * 4 + wv;
  float* dst = Gpart + (((size_t)pc * B + b) * HEADS + h) * 1024;
#pragma unroll
  for (int a = 0; a < 4; ++a)
#pragma unroll
    for (int bb = 0; bb < 4; ++bb) dst[(i0 + a) * 32 + (j0 + bb)] = acc[a][bb];
  __syncthreads();
#pragma unroll
  for (int e = 0; e < 8; ++e) {
    flq[t * 8 + e] = sq[e];
    flk[t * 8 + e] = sk[e];
  }
  __syncthreads();
  if (t < 32) {
    const int tm = t >> 3, e = t & 7;
    float s1 = 0.f, s2 = 0.f;
    for (int k2 = 0; k2 < 64; ++k2) {
      const int tt = tm + k2 * 4;
      s1 += flq[tt * 8 + e];
      s2 += flk[tt * 8 + e];
    }
    ssq[((size_t)b * 16 + chunk) * C + h * 32 + t] = s1;
    ssk[((size_t)b * 16 + chunk) * C + h * 32 + t] = s2;
  }
}

// ---------------- reduce + normalize + softmax -> attn bf16 ----------------
__global__ __launch_bounds__(256) void softmax_kernel(
    const float* __restrict__ Gpart, const float* __restrict__ ssq,
    const float* __restrict__ ssk, const float* __restrict__ rescale,
    unsigned short* __restrict__ attnb) {
  const int h = blockIdx.x, b = blockIdx.y;
  const int t = threadIdx.x;
  __shared__ float G[1024];
  __shared__ float nq[32], nk[32];
#pragma unroll
  for (int e = 0; e < 4; ++e) {
    const int cell = e * 256 + t;
    float s = 0.f;
    for (int pc = 0; pc < 64; ++pc)
      s += Gpart[(((size_t)pc * B + b) * HEADS + h) * 1024 + cell];
    G[cell] = s;
  }
  if (t < 64) {
    const int d = t & 31;
    const float* ss = (t < 32) ? ssq : ssk;
    float s = 0.f;
    for (int ch = 0; ch < 16; ++ch) s += ss[((size_t)b * 16 + ch) * C + h * 32 + d];
    const float nn = fmaxf(sqrtf(s), 1e-12f);
    if (t < 32) nq[d] = nn;
    else nk[d] = nn;
  }
  __syncthreads();
  if (t < 32) {
    const int i = t;
    const float rs = rescale[h];
    float row[32];
    float mx = -1e30f;
#pragma unroll
    for (int j = 0; j < 32; ++j) {
      const float v = G[i * 32 + j] / (nk[i] * nq[j]) * rs;
      row[j] = v;
      mx = fmaxf(mx, v);
    }
    float sum = 0.f;
#pragma unroll
    for (int j = 0; j < 32; ++j) {
      const float e = expf(row[j] - mx);
      row[j] = e;
      sum += e;
    }
    const float inv = 1.f / sum;
#pragma unroll
    for (int j = 0; j < 32; ++j)
      attnb[(((size_t)b * HEADS + h) * 32 + i) * 32 + j] = f2bf(row[j] * inv);
  }
}

// ---------------- Weff[b][o][32h+j] = sum_i attn[b,h,i,j] * wprojT[o][32h+i] ------------
__global__ __launch_bounds__(256) void weff_kernel(const unsigned short* __restrict__ attnb,
                                                   const unsigned short* __restrict__ wprojT,
                                                   unsigned short* __restrict__ weff) {
  const int b = blockIdx.y;
  const int co0 = blockIdx.x * 64;
  const int t = threadIdx.x;
  __shared__ float att[8192];
  for (int e = t; e < 8192; e += 256) att[e] = bf2f(attnb[(size_t)b * 8192 + e]);
  __syncthreads();
  const int o = co0 + (t & 63);
  const int hq = t >> 6;
#pragma unroll
  for (int hh = 0; hh < 2; ++hh) {
    const int h = hq * 2 + hh;
    float wp[32];
#pragma unroll
    for (int i = 0; i < 32; ++i) wp[i] = bf2f(wprojT[(size_t)o * 256 + h * 32 + i]);
    for (int j4 = 0; j4 < 8; ++j4) {
      f32x4 s = {0.f, 0.f, 0.f, 0.f};
#pragma unroll
      for (int i = 0; i < 32; ++i) {
        const f32x4 a4 = *(const f32x4*)&att[(h * 32 + i) * 32 + j4 * 4];
        s += wp[i] * a4;
      }
      s16x4 oo;
#pragma unroll
      for (int e = 0; e < 4; ++e) oo[e] = (short)f2bf(s[e]);
      *(s16x4*)&weff[((size_t)b * 256 + o) * 256 + h * 32 + j4 * 4] = oo;
    }
  }
}

// ---------------- depthwise 3x3, 4 channels/thread ----------------
__global__ __launch_bounds__(512) void dw3_kernel(const unsigned short* __restrict__ in,
                                                  const float* __restrict__ wgt,
                                                  unsigned short* __restrict__ out_bf,
                                                  const int do_gelu) {
  const int y = blockIdx.x;
  const int b = blockIdx.y;
  const int t = threadIdx.x;
  const int cg = (t & 63) * 4;
  const int x0 = (t >> 6) * 16;
  float w[9][4];
#pragma unroll
  for (int e = 0; e < 9; ++e)
#pragma unroll
    for (int ch = 0; ch < 4; ++ch) w[e][ch] = wgt[(cg + ch) * 9 + e];
  const int ym = y - 1, yp = y + 1;
  const bool hm = (ym >= 0), hp = (yp < HW);
  const size_t base = (size_t)b * NTOK * C + cg;
  auto ld4 = [&](int yy, int xx) -> f32x4 {
    const s16x4 v = *(const s16x4*)&in[base + ((size_t)yy * HW + xx) * C];
    f32x4 f;
    f[0] = bf2f((unsigned short)v[0]);
    f[1] = bf2f((unsigned short)v[1]);
    f[2] = bf2f((unsigned short)v[2]);
    f[3] = bf2f((unsigned short)v[3]);
    return f;
  };
  const f32x4 zero = {0.f, 0.f, 0.f, 0.f};
  f32x4 a0, a1, a2, b0, b1, b2;
  if (x0 > 0) {
    a0 = hm ? ld4(ym, x0 - 1) : zero;
    a1 = ld4(y, x0 - 1);
    a2 = hp ? ld4(yp, x0 - 1) : zero;
  } else {
    a0 = a1 = a2 = zero;
  }
  b0 = hm ? ld4(ym, x0) : zero;
  b1 = ld4(y, x0);
  b2 = hp ? ld4(yp, x0) : zero;
  for (int xi = 0; xi < 16; ++xi) {
    const int x = x0 + xi;
    f32x4 c0, c1, c2;
    if (x + 1 < HW) {
      c0 = hm ? ld4(ym, x + 1) : zero;
      c1 = ld4(y, x + 1);
      c2 = hp ? ld4(yp, x + 1) : zero;
    } else {
      c0 = c1 = c2 = zero;
    }
    float res[4];
#pragma unroll
    for (int ch = 0; ch < 4; ++ch) {
      float r = w[0][ch] * a0[ch] + w[1][ch] * b0[ch] + w[2][ch] * c0[ch] +
                w[3][ch] * a1[ch] + w[4][ch] * b1[ch] + w[5][ch] * c1[ch] +
                w[6][ch] * a2[ch] + w[7][ch] * b2[ch] + w[8][ch] * c2[ch];
      if (do_gelu) r = 0.5f * r * (1.f + erff(r * 0.70710678118654752f));
      res[ch] = r;
    }
    const size_t oi = base + ((size_t)y * HW + x) * C;
    s16x4 o;
    o[0] = (short)f2bf(res[0]);
    o[1] = (short)f2bf(res[1]);
    o[2] = (short)f2bf(res[2]);
    o[3] = (short)f2bf(res[3]);
    *(s16x4*)&out_bf[oi] = o;
    a0 = b0; a1 = b1; a2 = b2;
    b0 = c0; b1 = c1; b2 = c2;
  }
}

extern "C" void kernel_launch(void* const* d_in, const int* in_sizes, int n_in, void* d_out,
                              int out_size, void* d_ws, size_t ws_size, hipStream_t stream) {
  (void)in_sizes; (void)n_in; (void)out_size; (void)ws_size;
  const float* x = (const float*)d_in[0];
  const float* maskp = (const float*)d_in[1];
  const float* wq = (const float*)d_in[2];
  const float* wk = (const float*)d_in[3];
  const float* wv = (const float*)d_in[4];
  const float* rescale = (const float*)d_in[5];
  const float* wproj = (const float*)d_in[6];
  const float* bproj = (const float*)d_in[7];
  const float* mg_w1 = (const float*)d_in[8];
  const float* mg_b1 = (const float*)d_in[9];
  const float* mg_w2 = (const float*)d_in[10];
  const float* mg_b2 = (const float*)d_in[11];
  const float* mg_dw = (const float*)d_in[12];
  const float* mg_db = (const float*)d_in[13];
  const float* be_w1 = (const float*)d_in[14];
  const float* be_w2 = (const float*)d_in[15];
  float* out = (float*)d_out;
  char* ws = (char*)d_ws;

  unsigned short* qb = (unsigned short*)(ws + 33554432ull);     // 32MB, later y1
  unsigned short* kb = (unsigned short*)(ws + 67108864ull);     // 32MB, later y2
  unsigned short* vb = (unsigned short*)(ws + 100663296ull);    // 32MB
  unsigned short* mT = (unsigned short*)(ws + 134217728ull);    // 8MB, later mask_emb
  unsigned short* m1b = (unsigned short*)(ws + 142606336ull);   // 8MB, later Weff
  unsigned short* m2b = (unsigned short*)(ws + 150994944ull);   // 8MB, later Gpart
  unsigned short* wqkvT = (unsigned short*)(ws + 159383552ull); // 384KB
  unsigned short* wprojT = (unsigned short*)(ws + 159776768ull);// 128KB
  unsigned short* w1b = (unsigned short*)(ws + 159907840ull);   // 128KB
  unsigned short* w2b = (unsigned short*)(ws + 160038912ull);   // 128KB
  float* ssq = (float*)(ws + 160169984ull);                     // 64KB
  float* ssk = (float*)(ws + 160432128ull);                     // 64KB
  unsigned short* attnb = (unsigned short*)(ws + 160694272ull); // 64KB
  float* Gpart = (float*)m2b;
  unsigned short* memb = mT;
  unsigned short* y1 = qb;
  unsigned short* y2 = kb;
  unsigned short* weff = m1b;

  prep_w_kernel<<<dim3(256, 6), 256, 0, stream>>>(wq, wk, wv, wproj, mg_w1, mg_w2, wqkvT,
                                                  wprojT, w1b, w2b);
  tmask_kernel<<<dim3(512, 8), 1024, 0, stream>>>(maskp, mT);
  // mask branch
  gemm_bt_kernel<<<256, 256, 0, stream>>>(mT, w1b, 256, 2, 1, m1b, mg_b1);
  gemm_bt_kernel<<<256, 256, 0, stream>>>(m1b, w2b, 256, 2, 1, m2b, mg_b2);
  mask_dw5_kernel<<<dim3(8, 128), 256, 0, stream>>>(m2b, m1b, mg_dw, mg_db, memb);
  // q,k,v straight from f32 x (cast fused into A reg-staging), 256 M-tiles x 3 N-panels
  gemm256_qkv_kernel<<<768, 512, 0, stream>>>(x, wqkvT, qb, kb, vb);
  gram_kernel<<<dim3(16, 8, 4), 256, 0, stream>>>(qb, kb, Gpart, ssq, ssk);
  softmax_kernel<<<dim3(8, 4), 256, 0, stream>>>(Gpart, ssq, ssk, rescale, attnb);
  weff_kernel<<<dim3(4, 4), 256, 0, stream>>>(attnb, wprojT, weff);
  // band branch: y1 = gelu(dw3(v)); y2 = dw3(y1)
  dw3_kernel<<<dim3(128, 4), 512, 0, stream>>>(vb, be_w1, y1, 1);
  dw3_kernel<<<dim3(128, 4), 512, 0, stream>>>(y1, be_w2, y2, 0);
  // proj: out = (v*memb) @ Weff_b^T + bproj + y2  (vma fused into A reg-staging)
  gemm256_proj_kernel<<<256, 512, 0, stream>>>(vb, memb, weff, bproj, y2, out);
}